// Round 8
// baseline (247.020 us; speedup 1.0000x reference)
//
#include <hip/hip_runtime.h>
#include <hip/hip_bf16.h>
#include <stdint.h>

// SLAYER SNN pipeline, MI355X.
// Layouts: raw input NCHWT (t innermost). pooled0 NCTHW. x0/x1 t-tiled.
// Precision: conv/cumsum/scan path in f64. CRITICAL: per-output FP
// accumulation order must stay EXACTLY fixed (ci->kh->kw, a->bb, t asc).
// Canary: absmax must stay exactly 0.01953125 every round.
// R8: register-window conv loops (k2a: tile DS reads 392->140/thread;
// k4a: 4-row j-blocking, weight DS reads 1568->392/thread). Order preserved.

#define T_ 100

// ---------------- K1: avgpool4 on raw input, NCHWT -> NCTHW f64 --------------
__global__ __launch_bounds__(256) void k1_pool0(const float* __restrict__ in,
                                                double* __restrict__ out) {
    __shared__ double lds[64 * 101];
    int b = blockIdx.x;
    int h = b & 63, c = (b >> 6) & 1, n = b >> 7;
    const float* inb = in + ((size_t)((n * 2 + c) * 256 + 4 * h) * 256) * 100;
    for (int k = 0; k < 7; ++k) {
        int e = threadIdx.x + (k << 8);
        if (e < 1600) {
            int w = e / 25, tq = e % 25;
            double s0 = 0.0, s1 = 0.0, s2 = 0.0, s3 = 0.0;
            #pragma unroll
            for (int a = 0; a < 4; ++a) {
                #pragma unroll
                for (int bb = 0; bb < 4; ++bb) {
                    const float4 v = *reinterpret_cast<const float4*>(
                        &inb[((size_t)(a * 256 + 4 * w + bb)) * 100 + 4 * tq]);
                    s0 += (double)v.x;
                    s1 += (double)v.y;
                    s2 += (double)v.z;
                    s3 += (double)v.w;
                }
            }
            double* lp = &lds[w * 101 + 4 * tq];
            lp[0] = s0 * 0.0625;
            lp[1] = s1 * 0.0625;
            lp[2] = s2 * 0.0625;
            lp[3] = s3 * 0.0625;
        }
    }
    __syncthreads();
    double* outb = out + ((size_t)(n * 2 + c) * 100) * 4096 + h * 64;
    for (int k = 0; k < 25; ++k) {
        int oi = threadIdx.x + (k << 8);
        int t = oi >> 6, w = oi & 63;
        outb[(size_t)t * 4096 + w] = lds[w * 101 + t];
    }
}

// ------- K2a: conv7x7 (2->4ch) in f64, rolling register window ---------------
// grid 3200 = 8n * 100t * 4hs, block 256 (hq,w). pooled0 -> x0 t-tiled layout.
__global__ __launch_bounds__(256, 2) void k2a_conv0(const double* __restrict__ pooled0,
                                                    const float* __restrict__ wc0,
                                                    double* __restrict__ x0) {
    __shared__ double tile[2 * 22 * 70];   // 24640 B
    __shared__ double wlds[392];           // 4co x 2ci x 49
    int b = blockIdx.x;
    int hs = b & 3;
    int t = (b >> 2) % 100;
    int n = b / 400;
    int tid = threadIdx.x;

    for (int i = tid; i < 392; i += 256) wlds[i] = (double)wc0[i];
    // div-free tile load: 44 rows (2ci x 22), cols by lane. Zeros OOB.
    {
        int lane = tid & 63, wv = tid >> 6;
        for (int r = wv; r < 44; r += 4) {
            int ci = (r >= 22) ? 1 : 0;
            int row = r - ci * 22;
            int habs = hs * 16 + row - 3;
            const double* src =
                &pooled0[((size_t)((n * 2 + ci) * 100 + t)) * 4096 + habs * 64];
            double* dst = &tile[(ci * 22 + row) * 70];
            int wabs = lane - 3;
            bool hok = (unsigned)habs < 64u;
            dst[lane] = (hok && (unsigned)wabs < 64u) ? src[wabs] : 0.0;
            if (lane < 6) {
                int wabs2 = lane + 61;
                dst[lane + 64] = (hok && (unsigned)wabs2 < 64u) ? src[wabs2] : 0.0;
            }
        }
    }
    __syncthreads();

    int w = tid & 63, hq = tid >> 6;
    int hl0 = hq * 4;
    double acc[4][4];                      // [co][j]
    #pragma unroll
    for (int co = 0; co < 4; ++co)
        #pragma unroll
        for (int j = 0; j < 4; ++j) acc[co][j] = 0.0;

    double win[4][7];                      // rows hl0+kh+j, taps w..w+6
    for (int ci = 0; ci < 2; ++ci) {
        #pragma unroll
        for (int j = 0; j < 4; ++j) {
            const double* rp = &tile[(ci * 22 + hl0 + j) * 70 + w];
            #pragma unroll
            for (int k = 0; k < 7; ++k) win[j][k] = rp[k];
        }
        #pragma unroll
        for (int kh = 0; kh < 7; ++kh) {
            const double* wp = &wlds[ci * 49 + kh * 7];
            #pragma unroll
            for (int co = 0; co < 4; ++co) {
                double w0 = wp[co * 98 + 0], w1 = wp[co * 98 + 1];
                double w2 = wp[co * 98 + 2], w3 = wp[co * 98 + 3];
                double w4 = wp[co * 98 + 4], w5 = wp[co * 98 + 5];
                double w6 = wp[co * 98 + 6];
                #pragma unroll
                for (int j = 0; j < 4; ++j) {
                    // per-acc kw order ascending == original (ci->kh->kw).
                    acc[co][j] += win[j][0] * w0;
                    acc[co][j] += win[j][1] * w1;
                    acc[co][j] += win[j][2] * w2;
                    acc[co][j] += win[j][3] * w3;
                    acc[co][j] += win[j][4] * w4;
                    acc[co][j] += win[j][5] * w5;
                    acc[co][j] += win[j][6] * w6;
                }
            }
            if (kh < 6) {   // shift window, load one new row
                #pragma unroll
                for (int j = 0; j < 3; ++j)
                    #pragma unroll
                    for (int k = 0; k < 7; ++k) win[j][k] = win[j + 1][k];
                const double* rp = &tile[(ci * 22 + hl0 + kh + 4) * 70 + w];
                #pragma unroll
                for (int k = 0; k < 7; ++k) win[3][k] = rp[k];
            }
        }
    }
    #pragma unroll
    for (int co = 0; co < 4; ++co)
        #pragma unroll
        for (int j = 0; j < 4; ++j)
            x0[(((size_t)(n * 4 + co) * 64 + (hs * 16 + hl0 + j)) * 100 + t) * 64 + w] =
                acc[co][j];
}

// ------- K2b: scan0 + avgpool4 fused; x0 reads fully sequential --------------
__global__ __launch_bounds__(256) void k2b_scan0_pool(const double* __restrict__ x0,
                                                      float* __restrict__ pooled1) {
    __shared__ uint8_t lsp[10][256];
    int bid = blockIdx.x;
    int g = bid >> 4, hp = bid & 15;
    int tid = threadIdx.x;
    int r = tid >> 6, w = tid & 63;
    size_t base = ((size_t)(g * 64 + hp * 4 + r) * 100) * 64 + w;
    double p = 0.0;
    int cnt = 0;
    for (int tc = 0; tc < 10; ++tc) {
        double v[10];
        #pragma unroll
        for (int j = 0; j < 10; ++j)
            v[j] = x0[base + (size_t)(tc * 10 + j) * 64];
        #pragma unroll
        for (int j = 0; j < 10; ++j) {
            p += v[j];
            int sp = (p - (double)cnt) >= 1.0;
            cnt += sp;
            lsp[j][tid] = (uint8_t)sp;
        }
        __syncthreads();
        if (tid < 160) {
            int t = tid >> 4, wp = tid & 15;
            int isum = 0;
            #pragma unroll
            for (int rr = 0; rr < 4; ++rr) {
                uint32_t u = *reinterpret_cast<const uint32_t*>(&lsp[t][rr * 64 + 4 * wp]);
                isum += (int)(u & 0xffu) + (int)((u >> 8) & 0xffu) +
                        (int)((u >> 16) & 0xffu) + (int)(u >> 24);
            }
            pooled1[((size_t)g * 100 + tc * 10 + t) * 256 + hp * 16 + wp] =
                (float)isum * 0.0625f;
        }
        __syncthreads();
    }
}

// ------- K2 fused fallback (used only if ws_size is too small) ---------------
#define TC2 5
__global__ __launch_bounds__(128) void k2_conv0_scan(const double* __restrict__ pooled0,
                                                     const float* __restrict__ wc0,
                                                     uint8_t* __restrict__ s0) {
    __shared__ double tile[2 * 7 * TC2 * 70];
    int b = blockIdx.x;
    int h = b & 63, n = b >> 6;
    int tid = threadIdx.x;
    int w = tid & 63, cog = tid >> 6;
    int co0 = 2 * cog, co1 = co0 + 1;
    for (int i = tid; i < 2 * 7 * TC2 * 70; i += 128) tile[i] = 0.0;
    double p0 = 0.0, p1 = 0.0;
    int c0 = 0, c1 = 0;
    for (int ch = 0; ch < T_ / TC2; ++ch) {
        int t0 = ch * TC2;
        __syncthreads();
        for (int k = 0; k < 35; ++k) {
            int e = tid + (k << 7);
            int ww = e & 63, rowid = e >> 6;
            int ci = rowid / 35, rem = rowid % 35;
            int tt = rem / 7, r = rem % 7;
            int habs = h - 3 + r;
            if ((unsigned)habs < 64u)
                tile[((ci * 7 + r) * TC2 + tt) * 70 + ww + 3] =
                    pooled0[((size_t)((n * 2 + ci) * 100 + t0 + tt)) * 4096 + habs * 64 + ww];
        }
        __syncthreads();
        double acc0[TC2], acc1[TC2];
        #pragma unroll
        for (int tt = 0; tt < TC2; ++tt) { acc0[tt] = 0.0; acc1[tt] = 0.0; }
        for (int ci = 0; ci < 2; ++ci) {
            for (int kh = 0; kh < 7; ++kh) {
                const double* trow = &tile[((ci * 7 + kh) * TC2) * 70];
                const float* wr0 = &wc0[co0 * 98 + ci * 49 + kh * 7];
                const float* wr1 = &wc0[co1 * 98 + ci * 49 + kh * 7];
                #pragma unroll
                for (int kw = 0; kw < 7; ++kw) {
                    double wa = (double)wr0[kw];
                    double wb = (double)wr1[kw];
                    #pragma unroll
                    for (int tt = 0; tt < TC2; ++tt) {
                        double v = trow[tt * 70 + w + kw];
                        acc0[tt] += v * wa;
                        acc1[tt] += v * wb;
                    }
                }
            }
        }
        #pragma unroll
        for (int tt = 0; tt < TC2; ++tt) {
            size_t ob = ((size_t)((n * 4 + co0) * 100 + t0 + tt)) * 4096 + h * 64 + w;
            p0 += acc0[tt];
            int sp0 = (p0 - (double)c0) >= 1.0;
            c0 += sp0;
            s0[ob] = (uint8_t)sp0;
            size_t ob1 = ((size_t)((n * 4 + co1) * 100 + t0 + tt)) * 4096 + h * 64 + w;
            p1 += acc1[tt];
            int sp1 = (p1 - (double)c1) >= 1.0;
            c1 += sp1;
            s0[ob1] = (uint8_t)sp1;
        }
    }
}

// ---------------- K3: avgpool4 of spikes (fallback path only) ----------------
__global__ __launch_bounds__(256) void k3_pool1(const uint8_t* __restrict__ s0,
                                                float* __restrict__ pooled1) {
    int oi = blockIdx.x * 256 + threadIdx.x;
    int w = oi & 15, h = (oi >> 4) & 15;
    int tc = oi >> 8;
    int t = tc % 100, nc = tc / 100;
    const uint8_t* base = s0 + ((size_t)nc * 100 + t) * 4096;
    int isum = 0;
    #pragma unroll
    for (int a = 0; a < 4; ++a) {
        uint32_t v = *reinterpret_cast<const uint32_t*>(&base[(4 * h + a) * 64 + 4 * w]);
        isum += (int)(v & 0xffu) + (int)((v >> 8) & 0xffu) +
                (int)((v >> 16) & 0xffu) + (int)(v >> 24);
    }
    pooled1[oi] = (float)isum * 0.0625f;
}

// ---------------- K4a: conv7x7 (4->8ch) in f64, j-blocked, 64 threads --------
// grid 800 (n,t), block 64: w=tid&15, hq=tid>>4; each thread owns 4 h-rows x 8 co.
// Weight LDS broadcasts reused across 4 rows (1568 -> 392 reads/thread).
__global__ __launch_bounds__(64) void k4a_conv1(const float* __restrict__ pooled1,
                                                const float* __restrict__ wc1,
                                                double* __restrict__ x1) {
    __shared__ float tile[4 * 22 * 24];    // rows habs+3, cols wabs+3, zeros OOB
    __shared__ float wl[1568];             // 8co x 4ci x 49
    int b = blockIdx.x;
    int n = b / 100, t = b % 100;
    int tid = threadIdx.x;
    for (int i = tid; i < 1568; i += 64) wl[i] = wc1[i];
    for (int i = tid; i < 2112; i += 64) {
        int ci = i / 528, rem = i % 528;
        int r = rem / 24, c = rem % 24;
        int habs = r - 3, wabs = c - 3;
        float v = 0.f;
        if ((unsigned)habs < 16u && (unsigned)wabs < 16u)
            v = pooled1[((size_t)((n * 4 + ci) * 100 + t)) * 256 + habs * 16 + wabs];
        tile[i] = v;
    }
    __syncthreads();
    int w = tid & 15, hq = tid >> 4;
    int hl0 = hq * 4;
    double acc[8][4];                      // [co][j]
    #pragma unroll
    for (int co = 0; co < 8; ++co)
        #pragma unroll
        for (int j = 0; j < 4; ++j) acc[co][j] = 0.0;

    float win[4][7];
    for (int ci = 0; ci < 4; ++ci) {
        #pragma unroll
        for (int j = 0; j < 4; ++j) {
            const float* rp = &tile[(ci * 22 + hl0 + j) * 24 + w];
            #pragma unroll
            for (int k = 0; k < 7; ++k) win[j][k] = rp[k];
        }
        #pragma unroll
        for (int kh = 0; kh < 7; ++kh) {
            const float* wr = &wl[ci * 49 + kh * 7];
            #pragma unroll
            for (int co = 0; co < 8; ++co) {
                double w0 = (double)wr[co * 196 + 0], w1 = (double)wr[co * 196 + 1];
                double w2 = (double)wr[co * 196 + 2], w3 = (double)wr[co * 196 + 3];
                double w4 = (double)wr[co * 196 + 4], w5 = (double)wr[co * 196 + 5];
                double w6 = (double)wr[co * 196 + 6];
                #pragma unroll
                for (int j = 0; j < 4; ++j) {
                    // per-acc order ci->kh->kw ascending == original.
                    acc[co][j] += (double)win[j][0] * w0;
                    acc[co][j] += (double)win[j][1] * w1;
                    acc[co][j] += (double)win[j][2] * w2;
                    acc[co][j] += (double)win[j][3] * w3;
                    acc[co][j] += (double)win[j][4] * w4;
                    acc[co][j] += (double)win[j][5] * w5;
                    acc[co][j] += (double)win[j][6] * w6;
                }
            }
            if (kh < 6) {
                #pragma unroll
                for (int j = 0; j < 3; ++j)
                    #pragma unroll
                    for (int k = 0; k < 7; ++k) win[j][k] = win[j + 1][k];
                const float* rp = &tile[(ci * 22 + hl0 + kh + 4) * 24 + w];
                #pragma unroll
                for (int k = 0; k < 7; ++k) win[3][k] = rp[k];
            }
        }
    }
    #pragma unroll
    for (int co = 0; co < 8; ++co)
        #pragma unroll
        for (int j = 0; j < 4; ++j) {
            int hw = (hl0 + j) * 16 + w;
            x1[(((size_t)(n * 8 + co) * 4 + (hw >> 6)) * 100 + t) * 64 + (hw & 63)] =
                acc[co][j];
        }
}

// ---------------- K4b: cumsum + IAF scan for stage 2 -------------------------
__global__ __launch_bounds__(64) void k4b_scan1(const double* __restrict__ x1,
                                                uint8_t* __restrict__ s1) {
    int bid = blockIdx.x;
    int g8 = bid >> 2, q = bid & 3;
    size_t rbase = ((size_t)(g8 * 4 + q) * 100) * 64 + threadIdx.x;
    size_t wbase = (size_t)g8 * 100 * 256 + (q << 6) + threadIdx.x;
    double p = 0.0;
    int cnt = 0;
    for (int tc = 0; tc < 10; ++tc) {
        double v[10];
        #pragma unroll
        for (int j = 0; j < 10; ++j)
            v[j] = x1[rbase + (size_t)(tc * 10 + j) * 64];
        #pragma unroll
        for (int j = 0; j < 10; ++j) {
            p += v[j];
            int sp = (p - (double)cnt) >= 1.0;
            cnt += sp;
            s1[wbase + (size_t)(tc * 10 + j) * 256] = (uint8_t)sp;
        }
    }
}

// ---------------- K5: avgpool4 + dense, fused block reduction ----------------
__global__ __launch_bounds__(256) void k5_dense(const uint8_t* __restrict__ s1,
                                                const float* __restrict__ wd,
                                                float* __restrict__ out) {
    __shared__ float red[2][4];
    int b = blockIdx.x;
    int n = b / 100, t = b % 100;
    int tid = threadIdx.x;
    int c = tid >> 5, H = (tid >> 1) & 15, Wg = tid & 1;
    const uint8_t* sb = s1 + ((size_t)((n * 8 + c) * 100 + t)) * 256 + H * 16 + Wg * 8;
    float sumA = 0.f, sumB = 0.f;
    #pragma unroll
    for (int j = 0; j < 4; ++j) sumA += (float)sb[j];
    #pragma unroll
    for (int j = 4; j < 8; ++j) sumB += (float)sb[j];
    int wb = c * 16 + (H >> 2) * 4 + Wg * 2;
    float o0 = sumA * wd[wb] + sumB * wd[wb + 1];
    float o1 = sumA * wd[128 + wb] + sumB * wd[128 + wb + 1];
    #pragma unroll
    for (int off = 32; off > 0; off >>= 1) {
        o0 += __shfl_down(o0, off, 64);
        o1 += __shfl_down(o1, off, 64);
    }
    int lane = tid & 63, wid = tid >> 6;
    if (lane == 0) { red[0][wid] = o0; red[1][wid] = o1; }
    __syncthreads();
    if (tid == 0) {
        float a = (red[0][0] + red[0][1]) + (red[0][2] + red[0][3]);
        float bsum = (red[1][0] + red[1][1]) + (red[1][2] + red[1][3]);
        out[(size_t)(n * 2) * 100 + t] = a * 0.0625f;
        out[(size_t)(n * 2 + 1) * 100 + t] = bsum * 0.0625f;
    }
}

extern "C" void kernel_launch(void* const* d_in, const int* in_sizes, int n_in,
                              void* d_out, int out_size, void* d_ws, size_t ws_size,
                              hipStream_t stream) {
    const float* data = (const float*)d_in[0];
    const float* w0   = (const float*)d_in[1];
    const float* w1   = (const float*)d_in[2];
    const float* wd   = (const float*)d_in[3];
    float* out = (float*)d_out;
    char* ws = (char*)d_ws;

    const size_t NEED_SPLIT = 157286400;  // pooled0(52.4M) + x0(104.9M)

    if (ws_size >= NEED_SPLIT) {
        double*  pooled0 = (double*)(ws);                 // [0, 52428800)
        double*  x0      = (double*)(ws + 52428800);      // [52428800, 157286400)
        float*   pooled1 = (float*)(ws);                  // 3,276,800 B
        double*  x1      = (double*)(ws + 4194304);       // 16,384,000 B
        uint8_t* s1      = (uint8_t*)(ws + 25165824);     // 2,048,000 B

        k1_pool0<<<1024, 256, 0, stream>>>(data, pooled0);
        k2a_conv0<<<3200, 256, 0, stream>>>(pooled0, w0, x0);
        k2b_scan0_pool<<<512, 256, 0, stream>>>(x0, pooled1);
        k4a_conv1<<<800, 64, 0, stream>>>(pooled1, w1, x1);
        k4b_scan1<<<256, 64, 0, stream>>>(x1, s1);
        k5_dense<<<800, 256, 0, stream>>>(s1, wd, out);
    } else {
        double*  pooled0 = (double*)(ws);
        uint8_t* s0      = (uint8_t*)(ws + 52428800);
        float*   pooled1 = (float*)(ws + 65536000);
        double*  x1      = (double*)(ws + 68812800);
        uint8_t* s1      = (uint8_t*)(ws + 85196800);

        k1_pool0<<<1024, 256, 0, stream>>>(data, pooled0);
        k2_conv0_scan<<<512, 128, 0, stream>>>(pooled0, w0, s0);
        k3_pool1<<<3200, 256, 0, stream>>>(s0, pooled1);
        k4a_conv1<<<800, 64, 0, stream>>>(pooled1, w1, x1);
        k4b_scan1<<<256, 64, 0, stream>>>(x1, s1);
        k5_dense<<<800, 256, 0, stream>>>(s1, wd, out);
    }
}

// Round 9
// 235.791 us; speedup vs baseline: 1.0476x; 1.0476x over previous
//
#include <hip/hip_runtime.h>
#include <hip/hip_bf16.h>
#include <stdint.h>

// SLAYER SNN pipeline, MI355X. — R9: verbatim revert to the R7 champion
// (235.9 µs). R8's register-window experiment regressed (247) and is dropped.
// Layouts: raw input NCHWT (t innermost). pooled0 NCTHW. x0/x1 are t-tiled:
// x0[g=n*4+co][row 0..63][t 0..99][w 0..63]  -> scan waves stream 51.2KB seq.
// x1[g8=n*8+co][q 0..3][t 0..99][w 0..63]    -> scan waves stream 25.6KB seq.
// Precision: conv/cumsum/scan path in f64. CRITICAL: absmax is 0.0195 vs
// threshold 0.0208 -> per-output FP accumulation order must stay EXACTLY
// fixed (ci->kh->kw, a->bb, t ascending). Address-permutation changes only.
// Canary: absmax must stay exactly 0.01953125 every round.

#define T_ 100

// ---------------- K1: avgpool4 on raw input, NCHWT -> NCTHW f64 --------------
// grid 1024 (n,c,h'), block 256. float4-vectorized reads (4 t's per load).
__global__ __launch_bounds__(256) void k1_pool0(const float* __restrict__ in,
                                                double* __restrict__ out) {
    __shared__ double lds[64 * 101];
    int b = blockIdx.x;
    int h = b & 63, c = (b >> 6) & 1, n = b >> 7;
    const float* inb = in + ((size_t)((n * 2 + c) * 256 + 4 * h) * 256) * 100;
    // phase A: 1600 items = 64 w x 25 tq (4 t's each), float4 loads
    for (int k = 0; k < 7; ++k) {
        int e = threadIdx.x + (k << 8);
        if (e < 1600) {
            int w = e / 25, tq = e % 25;
            double s0 = 0.0, s1 = 0.0, s2 = 0.0, s3 = 0.0;
            #pragma unroll
            for (int a = 0; a < 4; ++a) {
                #pragma unroll
                for (int bb = 0; bb < 4; ++bb) {
                    const float4 v = *reinterpret_cast<const float4*>(
                        &inb[((size_t)(a * 256 + 4 * w + bb)) * 100 + 4 * tq]);
                    s0 += (double)v.x;   // same a->bb order as scalar version
                    s1 += (double)v.y;
                    s2 += (double)v.z;
                    s3 += (double)v.w;
                }
            }
            double* lp = &lds[w * 101 + 4 * tq];
            lp[0] = s0 * 0.0625;
            lp[1] = s1 * 0.0625;
            lp[2] = s2 * 0.0625;
            lp[3] = s3 * 0.0625;
        }
    }
    __syncthreads();
    // phase B: write NCTHW (lanes consecutive in w -> coalesced 512B stores)
    double* outb = out + ((size_t)(n * 2 + c) * 100) * 4096 + h * 64;
    for (int k = 0; k < 25; ++k) {
        int oi = threadIdx.x + (k << 8);
        int t = oi >> 6, w = oi & 63;
        outb[(size_t)t * 4096 + w] = lds[w * 101 + t];
    }
}

// ------- K2a: conv7x7 (2->4ch) in f64, fully parallel over (n,t,h-slab) -----
// grid 3200 = 8n * 100t * 4hs, block 256 (hq,w). pooled0 -> x0 t-tiled layout.
__global__ __launch_bounds__(256, 2) void k2a_conv0(const double* __restrict__ pooled0,
                                                    const float* __restrict__ wc0,
                                                    double* __restrict__ x0) {
    __shared__ double tile[2 * 22 * 70];   // 24640 B
    __shared__ double wlds[392];           // 4co x 2ci x 49
    int b = blockIdx.x;
    int hs = b & 3;
    int t = (b >> 2) % 100;
    int n = b / 400;
    int tid = threadIdx.x;

    for (int i = tid; i < 392; i += 256) wlds[i] = (double)wc0[i];
    // div-free tile load: 44 rows (2ci x 22), cols by lane. Zeros OOB.
    {
        int lane = tid & 63, wv = tid >> 6;
        for (int r = wv; r < 44; r += 4) {
            int ci = (r >= 22) ? 1 : 0;
            int row = r - ci * 22;
            int habs = hs * 16 + row - 3;
            const double* src =
                &pooled0[((size_t)((n * 2 + ci) * 100 + t)) * 4096 + habs * 64];
            double* dst = &tile[(ci * 22 + row) * 70];
            int wabs = lane - 3;
            bool hok = (unsigned)habs < 64u;
            dst[lane] = (hok && (unsigned)wabs < 64u) ? src[wabs] : 0.0;
            if (lane < 6) {
                int wabs2 = lane + 61;   // col lane+64 -> wabs = lane+64-3
                dst[lane + 64] = (hok && (unsigned)wabs2 < 64u) ? src[wabs2] : 0.0;
            }
        }
    }
    __syncthreads();

    int w = tid & 63, hq = tid >> 6;       // hq 0..3 -> local h rows hq*4..hq*4+3
    int hl0 = hq * 4;
    double acc[4][4];                      // [co][j]
    #pragma unroll
    for (int co = 0; co < 4; ++co)
        #pragma unroll
        for (int j = 0; j < 4; ++j) acc[co][j] = 0.0;

    for (int ci = 0; ci < 2; ++ci) {
        #pragma unroll
        for (int kh = 0; kh < 7; ++kh) {
            const double* wp = &wlds[ci * 49 + kh * 7];
            #pragma unroll
            for (int j = 0; j < 4; ++j) {
                const double* r = &tile[(ci * 22 + hl0 + kh + j) * 70 + w];
                double v0 = r[0], v1 = r[1], v2 = r[2], v3 = r[3];
                double v4 = r[4], v5 = r[5], v6 = r[6];
                #pragma unroll
                for (int co = 0; co < 4; ++co) {
                    // per-acc accumulation order over kw ascending == original.
                    acc[co][j] += v0 * wp[co * 98 + 0];
                    acc[co][j] += v1 * wp[co * 98 + 1];
                    acc[co][j] += v2 * wp[co * 98 + 2];
                    acc[co][j] += v3 * wp[co * 98 + 3];
                    acc[co][j] += v4 * wp[co * 98 + 4];
                    acc[co][j] += v5 * wp[co * 98 + 5];
                    acc[co][j] += v6 * wp[co * 98 + 6];
                }
            }
        }
    }
    #pragma unroll
    for (int co = 0; co < 4; ++co)
        #pragma unroll
        for (int j = 0; j < 4; ++j)
            x0[(((size_t)(n * 4 + co) * 64 + (hs * 16 + hl0 + j)) * 100 + t) * 64 + w] =
                acc[co][j];
}

// ------- K2b: scan0 + avgpool4 fused; x0 reads fully sequential --------------
// grid 512 = 32g(n*4+co) x 16hp, block 256 (r=tid>>6 raw row, w=tid&63).
// Each wave streams x0[g][hp*4+r][0..99][0..63] = 51.2 KB contiguous.
__global__ __launch_bounds__(256) void k2b_scan0_pool(const double* __restrict__ x0,
                                                      float* __restrict__ pooled1) {
    __shared__ uint8_t lsp[10][256];
    int bid = blockIdx.x;
    int g = bid >> 4, hp = bid & 15;
    int tid = threadIdx.x;
    int r = tid >> 6, w = tid & 63;
    size_t base = ((size_t)(g * 64 + hp * 4 + r) * 100) * 64 + w;
    double p = 0.0;
    int cnt = 0;
    for (int tc = 0; tc < 10; ++tc) {
        double v[10];
        #pragma unroll
        for (int j = 0; j < 10; ++j)
            v[j] = x0[base + (size_t)(tc * 10 + j) * 64];   // 10 loads in flight
        #pragma unroll
        for (int j = 0; j < 10; ++j) {
            p += v[j];                                       // same t order
            int sp = (p - (double)cnt) >= 1.0;
            cnt += sp;
            lsp[j][tid] = (uint8_t)sp;
        }
        __syncthreads();
        if (tid < 160) {
            int t = tid >> 4, wp = tid & 15;
            int isum = 0;
            #pragma unroll
            for (int rr = 0; rr < 4; ++rr) {
                uint32_t u = *reinterpret_cast<const uint32_t*>(&lsp[t][rr * 64 + 4 * wp]);
                isum += (int)(u & 0xffu) + (int)((u >> 8) & 0xffu) +
                        (int)((u >> 16) & 0xffu) + (int)(u >> 24);
            }
            pooled1[((size_t)g * 100 + tc * 10 + t) * 256 + hp * 16 + wp] =
                (float)isum * 0.0625f;
        }
        __syncthreads();
    }
}

// ------- K2 fused fallback (used only if ws_size is too small) ---------------
#define TC2 5
__global__ __launch_bounds__(128) void k2_conv0_scan(const double* __restrict__ pooled0,
                                                     const float* __restrict__ wc0,
                                                     uint8_t* __restrict__ s0) {
    __shared__ double tile[2 * 7 * TC2 * 70];
    int b = blockIdx.x;
    int h = b & 63, n = b >> 6;
    int tid = threadIdx.x;
    int w = tid & 63, cog = tid >> 6;
    int co0 = 2 * cog, co1 = co0 + 1;
    for (int i = tid; i < 2 * 7 * TC2 * 70; i += 128) tile[i] = 0.0;
    double p0 = 0.0, p1 = 0.0;
    int c0 = 0, c1 = 0;
    for (int ch = 0; ch < T_ / TC2; ++ch) {
        int t0 = ch * TC2;
        __syncthreads();
        for (int k = 0; k < 35; ++k) {
            int e = tid + (k << 7);
            int ww = e & 63, rowid = e >> 6;
            int ci = rowid / 35, rem = rowid % 35;
            int tt = rem / 7, r = rem % 7;
            int habs = h - 3 + r;
            if ((unsigned)habs < 64u)
                tile[((ci * 7 + r) * TC2 + tt) * 70 + ww + 3] =
                    pooled0[((size_t)((n * 2 + ci) * 100 + t0 + tt)) * 4096 + habs * 64 + ww];
        }
        __syncthreads();
        double acc0[TC2], acc1[TC2];
        #pragma unroll
        for (int tt = 0; tt < TC2; ++tt) { acc0[tt] = 0.0; acc1[tt] = 0.0; }
        for (int ci = 0; ci < 2; ++ci) {
            for (int kh = 0; kh < 7; ++kh) {
                const double* trow = &tile[((ci * 7 + kh) * TC2) * 70];
                const float* wr0 = &wc0[co0 * 98 + ci * 49 + kh * 7];
                const float* wr1 = &wc0[co1 * 98 + ci * 49 + kh * 7];
                #pragma unroll
                for (int kw = 0; kw < 7; ++kw) {
                    double wa = (double)wr0[kw];
                    double wb = (double)wr1[kw];
                    #pragma unroll
                    for (int tt = 0; tt < TC2; ++tt) {
                        double v = trow[tt * 70 + w + kw];
                        acc0[tt] += v * wa;
                        acc1[tt] += v * wb;
                    }
                }
            }
        }
        #pragma unroll
        for (int tt = 0; tt < TC2; ++tt) {
            size_t ob = ((size_t)((n * 4 + co0) * 100 + t0 + tt)) * 4096 + h * 64 + w;
            p0 += acc0[tt];
            int sp0 = (p0 - (double)c0) >= 1.0;
            c0 += sp0;
            s0[ob] = (uint8_t)sp0;
            size_t ob1 = ((size_t)((n * 4 + co1) * 100 + t0 + tt)) * 4096 + h * 64 + w;
            p1 += acc1[tt];
            int sp1 = (p1 - (double)c1) >= 1.0;
            c1 += sp1;
            s0[ob1] = (uint8_t)sp1;
        }
    }
}

// ---------------- K3: avgpool4 of spikes (fallback path only) ----------------
__global__ __launch_bounds__(256) void k3_pool1(const uint8_t* __restrict__ s0,
                                                float* __restrict__ pooled1) {
    int oi = blockIdx.x * 256 + threadIdx.x;
    int w = oi & 15, h = (oi >> 4) & 15;
    int tc = oi >> 8;
    int t = tc % 100, nc = tc / 100;
    const uint8_t* base = s0 + ((size_t)nc * 100 + t) * 4096;
    int isum = 0;
    #pragma unroll
    for (int a = 0; a < 4; ++a) {
        uint32_t v = *reinterpret_cast<const uint32_t*>(&base[(4 * h + a) * 64 + 4 * w]);
        isum += (int)(v & 0xffu) + (int)((v >> 8) & 0xffu) +
                (int)((v >> 16) & 0xffu) + (int)(v >> 24);
    }
    pooled1[oi] = (float)isum * 0.0625f;
}

// ---------------- K4a: conv7x7 (4->8ch) in f64, weights in LDS ---------------
// x1 written in t-tiled layout [g8][q=hw>>6][t][w=hw&63].
__global__ __launch_bounds__(256) void k4a_conv1(const float* __restrict__ pooled1,
                                                 const float* __restrict__ wc1,
                                                 double* __restrict__ x1) {
    __shared__ float tile[4 * 22 * 24];
    __shared__ float wl[1568];             // 8co x 4ci x 49
    int b = blockIdx.x;
    int n = b / 100, t = b % 100;
    int tid = threadIdx.x;
    for (int i = tid; i < 4 * 22 * 24; i += 256) tile[i] = 0.0f;
    for (int i = tid; i < 1568; i += 256) wl[i] = wc1[i];
    __syncthreads();
    for (int k = 0; k < 4; ++k) {
        int e = tid + (k << 8);
        int w = e & 15, rowid = e >> 4;
        int ci = rowid >> 4, hr3 = rowid & 15;
        tile[(ci * 22 + hr3 + 3) * 24 + 3 + w] =
            pooled1[((size_t)((n * 4 + ci) * 100 + t)) * 256 + hr3 * 16 + w];
    }
    __syncthreads();
    int h = tid >> 4, w = tid & 15;
    double acc[8];
    #pragma unroll
    for (int co = 0; co < 8; ++co) acc[co] = 0.0;
    for (int ci = 0; ci < 4; ++ci) {
        for (int kh = 0; kh < 7; ++kh) {
            const float* trow = &tile[(ci * 22 + h + kh) * 24];
            const float* wr = &wl[ci * 49 + kh * 7];
            #pragma unroll
            for (int kw = 0; kw < 7; ++kw) {
                double v = (double)trow[w + kw];
                #pragma unroll
                for (int co = 0; co < 8; ++co)
                    acc[co] += v * (double)wr[co * 196 + kw];
            }
        }
    }
    #pragma unroll
    for (int co = 0; co < 8; ++co)
        x1[(((size_t)(n * 8 + co) * 4 + (tid >> 6)) * 100 + t) * 64 + (tid & 63)] =
            acc[co];
}

// ---------------- K4b: cumsum + IAF scan for stage 2 -------------------------
// grid 256 blocks x 64 thr; each wave streams x1[g8][q][0..99][0..63] = 25.6KB
// sequential. s1 stays in the old [g8][t][256] layout for k5.
__global__ __launch_bounds__(64) void k4b_scan1(const double* __restrict__ x1,
                                                uint8_t* __restrict__ s1) {
    int bid = blockIdx.x;
    int g8 = bid >> 2, q = bid & 3;
    size_t rbase = ((size_t)(g8 * 4 + q) * 100) * 64 + threadIdx.x;
    size_t wbase = (size_t)g8 * 100 * 256 + (q << 6) + threadIdx.x;
    double p = 0.0;
    int cnt = 0;
    for (int tc = 0; tc < 10; ++tc) {
        double v[10];
        #pragma unroll
        for (int j = 0; j < 10; ++j)
            v[j] = x1[rbase + (size_t)(tc * 10 + j) * 64];
        #pragma unroll
        for (int j = 0; j < 10; ++j) {
            p += v[j];
            int sp = (p - (double)cnt) >= 1.0;
            cnt += sp;
            s1[wbase + (size_t)(tc * 10 + j) * 256] = (uint8_t)sp;
        }
    }
}

// ---------------- K5: avgpool4 + dense, fused block reduction ----------------
__global__ __launch_bounds__(256) void k5_dense(const uint8_t* __restrict__ s1,
                                                const float* __restrict__ wd,
                                                float* __restrict__ out) {
    __shared__ float red[2][4];
    int b = blockIdx.x;
    int n = b / 100, t = b % 100;
    int tid = threadIdx.x;
    int c = tid >> 5, H = (tid >> 1) & 15, Wg = tid & 1;
    const uint8_t* sb = s1 + ((size_t)((n * 8 + c) * 100 + t)) * 256 + H * 16 + Wg * 8;
    float sumA = 0.f, sumB = 0.f;
    #pragma unroll
    for (int j = 0; j < 4; ++j) sumA += (float)sb[j];
    #pragma unroll
    for (int j = 4; j < 8; ++j) sumB += (float)sb[j];
    int wb = c * 16 + (H >> 2) * 4 + Wg * 2;
    float o0 = sumA * wd[wb] + sumB * wd[wb + 1];
    float o1 = sumA * wd[128 + wb] + sumB * wd[128 + wb + 1];
    #pragma unroll
    for (int off = 32; off > 0; off >>= 1) {
        o0 += __shfl_down(o0, off, 64);
        o1 += __shfl_down(o1, off, 64);
    }
    int lane = tid & 63, wid = tid >> 6;
    if (lane == 0) { red[0][wid] = o0; red[1][wid] = o1; }
    __syncthreads();
    if (tid == 0) {
        float a = (red[0][0] + red[0][1]) + (red[0][2] + red[0][3]);
        float bsum = (red[1][0] + red[1][1]) + (red[1][2] + red[1][3]);
        out[(size_t)(n * 2) * 100 + t] = a * 0.0625f;
        out[(size_t)(n * 2 + 1) * 100 + t] = bsum * 0.0625f;
    }
}

extern "C" void kernel_launch(void* const* d_in, const int* in_sizes, int n_in,
                              void* d_out, int out_size, void* d_ws, size_t ws_size,
                              hipStream_t stream) {
    const float* data = (const float*)d_in[0];
    const float* w0   = (const float*)d_in[1];
    const float* w1   = (const float*)d_in[2];
    const float* wd   = (const float*)d_in[3];
    float* out = (float*)d_out;
    char* ws = (char*)d_ws;

    const size_t NEED_SPLIT = 157286400;  // pooled0(52.4M) + x0(104.9M)

    if (ws_size >= NEED_SPLIT) {
        // split path. x0 lives at [52.4M, 157.3M); pooled0 at [0, 52.4M) dies
        // after k2a, so pooled1/x1/s1 reuse its region (all < 52.4M offsets).
        double*  pooled0 = (double*)(ws);                 // [0, 52428800)
        double*  x0      = (double*)(ws + 52428800);      // [52428800, 157286400)
        float*   pooled1 = (float*)(ws);                  // 3,276,800 B
        double*  x1      = (double*)(ws + 4194304);       // 16,384,000 B
        uint8_t* s1      = (uint8_t*)(ws + 25165824);     // 2,048,000 B

        k1_pool0<<<1024, 256, 0, stream>>>(data, pooled0);
        k2a_conv0<<<3200, 256, 0, stream>>>(pooled0, w0, x0);
        k2b_scan0_pool<<<512, 256, 0, stream>>>(x0, pooled1);
        k4a_conv1<<<800, 256, 0, stream>>>(pooled1, w1, x1);
        k4b_scan1<<<256, 64, 0, stream>>>(x1, s1);
        k5_dense<<<800, 256, 0, stream>>>(s1, wd, out);
    } else {
        // fallback: fused conv0+scan (slower but fits 87.2 MB)
        double*  pooled0 = (double*)(ws);
        uint8_t* s0      = (uint8_t*)(ws + 52428800);
        float*   pooled1 = (float*)(ws + 65536000);
        double*  x1      = (double*)(ws + 68812800);
        uint8_t* s1      = (uint8_t*)(ws + 85196800);

        k1_pool0<<<1024, 256, 0, stream>>>(data, pooled0);
        k2_conv0_scan<<<512, 128, 0, stream>>>(pooled0, w0, s0);
        k3_pool1<<<3200, 256, 0, stream>>>(s0, pooled1);
        k4a_conv1<<<800, 256, 0, stream>>>(pooled1, w1, x1);
        k4b_scan1<<<256, 64, 0, stream>>>(x1, s1);
        k5_dense<<<800, 256, 0, stream>>>(s1, wd, out);
    }
}